// Round 6
// baseline (208.318 us; speedup 1.0000x reference)
//
#include <hip/hip_runtime.h>
#include <hip/hip_bf16.h>
#include <stdint.h>

#define B_ 16
#define N_ 2048
#define D_ 128

typedef __bf16 bf16_t;
typedef bf16_t bf16x8 __attribute__((ext_vector_type(8)));
typedef float f32x4 __attribute__((ext_vector_type(4)));

// ---------------- K0: pack adj (fp32 0/1 matrix) into bitmask ----------------
__global__ __launch_bounds__(256) void k_pack_adj(const float* __restrict__ adj,
                                                  unsigned int* __restrict__ bits) {
    int t = blockIdx.x * 256 + threadIdx.x;       // over N*N
    float v = adj[t];
    unsigned long long m = __ballot(v > 0.5f);
    if ((t & 63) == 0) {
        int i = t >> 11;
        int j = t & 2047;
        bits[i * 64 + (j >> 5)]     = (unsigned int)m;
        bits[i * 64 + (j >> 5) + 1] = (unsigned int)(m >> 32);
    }
}

// ---------------- K1: emb GEMM (64n x 128d tile) + fused q/k + exps ----------
// Pb[b][d][n] = bf16( sum_k x[b][n][k]*W[d][k] + be[d] )   (raw seq_fts, bf16)
__global__ __launch_bounds__(256, 2) void k_emb(const float* __restrict__ x,
                                                const float* __restrict__ W,
                                                const float* __restrict__ be,
                                                const float* __restrict__ wq,
                                                const float* __restrict__ bq,
                                                const float* __restrict__ wk,
                                                const float* __restrict__ bk,
                                                bf16_t* __restrict__ Pb,
                                                float* __restrict__ qa, float* __restrict__ ka,
                                                float* __restrict__ Eq, float* __restrict__ eqs,
                                                float* __restrict__ Ek, float* __restrict__ eks) {
    __shared__ float xs[32][68];     // [k][n]  64n + pad
    __shared__ float ws[32][132];    // [k][d]  128d + pad
    __shared__ float qs[64], ks[64];
    int b  = blockIdx.y;
    int n0 = blockIdx.x * 64;
    int tid = threadIdx.x;
    int tx = tid & 15, ty = tid >> 4;   // tx: n-dir (4 n), ty: d-dir (8 d)
    if (tid < 64) { qs[tid] = 0.f; ks[tid] = 0.f; }

    float acc[4][8] = {};               // [n][d]
    f32x4 xr[2], wr[4];

    auto loadregs = [&](int kc) {
#pragma unroll
        for (int s = 0; s < 2; ++s) {
            int p = tid + 256 * s;
            int n = p >> 3, kq = p & 7;
            xr[s] = *(const f32x4*)(x + ((size_t)(b * N_ + n0 + n)) * D_ + kc * 32 + kq * 4);
        }
#pragma unroll
        for (int s = 0; s < 4; ++s) {
            int p = tid + 256 * s;
            int d = p >> 3, kq = p & 7;
            wr[s] = *(const f32x4*)(W + (size_t)d * D_ + kc * 32 + kq * 4);
        }
    };
    auto writelds = [&]() {
#pragma unroll
        for (int s = 0; s < 2; ++s) {
            int p = tid + 256 * s;
            int n = p >> 3, kq = p & 7;
#pragma unroll
            for (int u = 0; u < 4; ++u) xs[kq * 4 + u][n] = xr[s][u];
        }
#pragma unroll
        for (int s = 0; s < 4; ++s) {
            int p = tid + 256 * s;
            int d = p >> 3, kq = p & 7;
#pragma unroll
            for (int u = 0; u < 4; ++u) ws[kq * 4 + u][d] = wr[s][u];
        }
    };

    loadregs(0);
    for (int kc = 0; kc < 4; ++kc) {
        writelds();
        __syncthreads();
        if (kc < 3) loadregs(kc + 1);
#pragma unroll 4
        for (int k = 0; k < 32; ++k) {
            f32x4 xv  = *(const f32x4*)&xs[k][tx * 4];
            f32x4 wv0 = *(const f32x4*)&ws[k][ty * 8];
            f32x4 wv1 = *(const f32x4*)&ws[k][ty * 8 + 4];
#pragma unroll
            for (int i = 0; i < 4; ++i)
#pragma unroll
                for (int j = 0; j < 8; ++j)
                    acc[i][j] += xv[i] * ((j < 4) ? wv0[j] : wv1[j - 4]);
        }
        __syncthreads();
    }

    float qp[4] = {}, kp[4] = {};
#pragma unroll
    for (int j = 0; j < 8; ++j) {
        int d = ty * 8 + j;
        float bj  = be[d];
        float wqj = wq[d];
        float wkj = wk[d];
        f32x4 o;
        bf16_t ob[4];
#pragma unroll
        for (int i = 0; i < 4; ++i) {
            o[i] = acc[i][j] + bj;
            qp[i] += o[i] * wqj;
            kp[i] += o[i] * wkj;
            ob[i] = (bf16_t)o[i];
        }
        *(uint2*)(Pb + ((size_t)b * D_ + d) * N_ + n0 + tx * 4) = *(uint2*)ob;
    }
#pragma unroll
    for (int i = 0; i < 4; ++i) {
        atomicAdd(&qs[tx * 4 + i], qp[i]);
        atomicAdd(&ks[tx * 4 + i], kp[i]);
    }
    __syncthreads();
    if (tid < 64) {
        int idx = b * N_ + n0 + tid;
        float aq = qs[tid] + bq[0];
        float ak = ks[tid] + bk[0];
        qa[idx] = aq;          ka[idx] = ak;
        Eq[idx] = expf(aq);    eqs[idx] = expf(0.01f * aq);
        Ek[idx] = expf(ak);    eks[idx] = expf(0.01f * ak);
    }
}

// ---------------- K2: denom[b][j] = sum_i V(b,i,j) ---------------------------
__global__ __launch_bounds__(256) void k_denom(const unsigned int* __restrict__ bits,
                                               const float* __restrict__ qa,
                                               const float* __restrict__ ka,
                                               const float* __restrict__ Eq,
                                               const float* __restrict__ eqs,
                                               const float* __restrict__ Ek,
                                               const float* __restrict__ eks,
                                               float* __restrict__ denom) {
    int jt  = blockIdx.x;     // 0..7
    int b   = blockIdx.y;     // 0..15
    int seg = blockIdx.z;     // 0..7
    int j = jt * 256 + threadIdx.x;
    float qj  = qa[b * N_ + j];
    float Eqj = Eq[b * N_ + j];
    float eqj = eqs[b * N_ + j];
    int shift = j & 31;
    int wid   = j >> 5;
    float acc = 0.f;
    int i0 = seg * 256;
#pragma unroll 16
    for (int i = i0; i < i0 + 256; ++i) {
        float kk  = ka[b * N_ + i];
        float Ekk = Ek[b * N_ + i];
        float ekk = eks[b * N_ + i];
        unsigned int w = bits[i * 64 + wid];
        float z  = kk + qj;
        float f1 = z > 0.f ? Ekk : ekk;
        float f2 = z > 0.f ? Eqj : eqj;
        float v  = f1 * f2;
        acc += ((w >> shift) & 1u) ? v : 1.0f;
    }
    atomicAdd(&denom[b * N_ + j], acc);
}

// ---------------- K3: vals = A' @ P ------------------------------------------
// A'[i,j] = (edge ? exp(leaky(k_i+q_j)) : 1) * rcp(denom[j])  — built in regs.
// P = raw seq_fts bf16 (Pb). Block 64i x 128d, 4 waves (ig,dg) = 32i x 64d.
// B-tile dbuf via global_load_lds w=16 (XOR swizzle); all j-side inputs are
// register-pipelined one step ahead -> no memory waits inside a step.
__global__ __launch_bounds__(256, 2) void k_attn(const float* __restrict__ Eq,
                                                 const float* __restrict__ eqs,
                                                 const float* __restrict__ Ek,
                                                 const float* __restrict__ eks,
                                                 const float* __restrict__ denom,
                                                 const unsigned int* __restrict__ bits,
                                                 const bf16_t* __restrict__ Pb,
                                                 float* __restrict__ out) {
    __shared__ __align__(16) bf16_t ldsB[2][128 * 64];   // 32 KB, B dbuf
    int b     = blockIdx.y;
    int ibase = blockIdx.x * 64;
    int tid   = threadIdx.x;
    int w     = tid >> 6;          // 0..3
    int lane  = tid & 63;
    int m16   = lane & 15;
    int quad  = lane >> 4;
    int ig    = w & 1;             // i-group (32 i)
    int dg    = w >> 1;            // d-group (64 d)

    int iA = ibase + (2 * ig) * 16 + m16;
    int iB = iA + 16;
    float EkR0 = Ek[b * N_ + iA],  EkR1 = Ek[b * N_ + iB];
    float ekR0 = eks[b * N_ + iA], ekR1 = eks[b * N_ + iB];
    float TR0 = __builtin_amdgcn_rcpf(EkR0);   // exp(-k_i): z>0  <=>  Eq_j > TR
    float TR1 = __builtin_amdgcn_rcpf(EkR1);
    const unsigned int* brA = bits + (size_t)iA * 64;
    const unsigned int* brB = bits + (size_t)iB * 64;
    const float* Eqp = Eq    + b * N_;
    const float* eqp = eqs   + b * N_;
    const float* dnp = denom + b * N_;
    const bf16_t* PtB = Pb + (size_t)b * D_ * N_;

    f32x4 acc[2][4];   // [i-chunk][d-tile]
#pragma unroll
    for (int c = 0; c < 2; ++c)
#pragma unroll
        for (int nt = 0; nt < 4; ++nt) acc[c][nt] = (f32x4){0.f, 0.f, 0.f, 0.f};

    // ---- pipeline registers (parity-indexed; compile-time after unroll) ----
    f32x4 Ev[2][2][2], ev[2][2][2], dv[2][2][2];  // [par][hh][half4]
    uint2 mA[2], mB[2];

    auto ldj = [&](int par, int jb) {
#pragma unroll
        for (int hh = 0; hh < 2; ++hh) {
            int j0 = jb + hh * 32 + quad * 8;
            Ev[par][hh][0] = *(const f32x4*)(Eqp + j0);
            Ev[par][hh][1] = *(const f32x4*)(Eqp + j0 + 4);
            ev[par][hh][0] = *(const f32x4*)(eqp + j0);
            ev[par][hh][1] = *(const f32x4*)(eqp + j0 + 4);
            dv[par][hh][0] = *(const f32x4*)(dnp + j0);
            dv[par][hh][1] = *(const f32x4*)(dnp + j0 + 4);
        }
        mA[par] = *(const uint2*)&brA[jb >> 5];
        mB[par] = *(const uint2*)&brB[jb >> 5];
    };

    // Stage 128d x 64j bf16 tile (16 KB), XOR swizzle on the GLOBAL address.
    auto stage = [&](int bufi, int jb) {
#pragma unroll
        for (int t = 0; t < 4; ++t) {
            int off = t * 4096 + tid * 16;               // byte offset in tile
            int d   = off >> 7;                          // row (128 B = 64 j)
            int g   = ((off & 127) >> 4) ^ (d & 7);      // swizzled j-chunk
            const bf16_t* gp = PtB + (size_t)d * N_ + jb + g * 8;
            __builtin_amdgcn_global_load_lds(
                (const __attribute__((address_space(1))) void*)gp,
                (__attribute__((address_space(3))) void*)((char*)(&ldsB[bufi][0]) + off),
                16, 0, 0);
        }
    };

    stage(0, 0);
    ldj(0, 0);
    __syncthreads();                 // drain initial stage + step-0 regs
    int buf = 0;
#pragma unroll 1
    for (int s2 = 0; s2 < N_ / 128; ++s2) {
#pragma unroll
        for (int par = 0; par < 2; ++par) {
            int step = s2 * 2 + par;
            int jb = step * 64;
            if (step + 1 < N_ / 64) {
                stage(buf ^ 1, jb + 64);     // B prefetch for next step
                ldj(par ^ 1, jb + 64);       // j-side regs for next step
            }

            // ---- A-gen entirely from registers (no waits) ----
            bf16x8 af[2][2];   // [i-chunk][hh]
#pragma unroll
            for (int hh = 0; hh < 2; ++hh) {
                unsigned int wdA = hh ? mA[par].y : mA[par].x;
                unsigned int wdB = hh ? mB[par].y : mB[par].x;
#pragma unroll
                for (int t = 0; t < 8; ++t) {
                    float Eqj = (t < 4) ? Ev[par][hh][0][t] : Ev[par][hh][1][t - 4];
                    float eqj = (t < 4) ? ev[par][hh][0][t] : ev[par][hh][1][t - 4];
                    float dj  = (t < 4) ? dv[par][hh][0][t] : dv[par][hh][1][t - 4];
                    float rdj = __builtin_amdgcn_rcpf(dj);
                    int bit = quad * 8 + t;
                    {
                        bool c = Eqj > TR0;
                        float v = (c ? EkR0 : ekR0) * (c ? Eqj : eqj) * rdj;
                        af[0][hh][t] = (bf16_t)(((wdA >> bit) & 1u) ? v : rdj);
                    }
                    {
                        bool c = Eqj > TR1;
                        float v = (c ? EkR1 : ekR1) * (c ? Eqj : eqj) * rdj;
                        af[1][hh][t] = (bf16_t)(((wdB >> bit) & 1u) ? v : rdj);
                    }
                }
            }

            // ---- ds_read B-fragments + MFMA ----
#pragma unroll
            for (int hh = 0; hh < 2; ++hh) {
                int cph = ((hh * 4 + quad) ^ (m16 & 7)) * 8;
#pragma unroll
                for (int nt = 0; nt < 4; ++nt) {
                    int d = dg * 64 + nt * 16 + m16;
                    bf16x8 bf = *(const bf16x8*)&ldsB[buf][d * 64 + cph];
                    acc[0][nt] = __builtin_amdgcn_mfma_f32_16x16x32_bf16(af[0][hh], bf, acc[0][nt], 0, 0, 0);
                    acc[1][nt] = __builtin_amdgcn_mfma_f32_16x16x32_bf16(af[1][hh], bf, acc[1][nt], 0, 0, 0);
                }
            }
            __syncthreads();   // drains next-step prefetch + guards ldsB reuse
            buf ^= 1;
        }
    }

    // ---- epilogue: C layout col=lane&15 (d), row=quad*4+r (i) ----
#pragma unroll
    for (int c = 0; c < 2; ++c) {
        int irow = ibase + (2 * ig + c) * 16 + quad * 4;
#pragma unroll
        for (int nt = 0; nt < 4; ++nt) {
            int d = dg * 64 + nt * 16 + m16;
#pragma unroll
            for (int r = 0; r < 4; ++r)
                out[((size_t)b * N_ + irow + r) * D_ + d] = acc[c][nt][r];
        }
    }
}

extern "C" void kernel_launch(void* const* d_in, const int* in_sizes, int n_in,
                              void* d_out, int out_size, void* d_ws, size_t ws_size,
                              hipStream_t stream) {
    const float* x   = (const float*)d_in[0];
    const float* adj = (const float*)d_in[1];
    const float* W   = (const float*)d_in[2];
    const float* be  = (const float*)d_in[3];
    const float* wq  = (const float*)d_in[4];
    const float* bq  = (const float*)d_in[5];
    const float* wk  = (const float*)d_in[6];
    const float* bk  = (const float*)d_in[7];
    float* out = (float*)d_out;

    char* ws = (char*)d_ws;
    size_t off = 0;
    bf16_t* Pb = (bf16_t*)(ws + off); off += (size_t)B_ * D_ * N_ * 2;   // 8 MB
    float* qa  = (float*)(ws + off);  off += (size_t)B_ * N_ * 4;
    float* ka  = (float*)(ws + off);  off += (size_t)B_ * N_ * 4;
    float* denom = (float*)(ws + off); off += (size_t)B_ * N_ * 4;
    float* Eq  = (float*)(ws + off);  off += (size_t)B_ * N_ * 4;
    float* eqs = (float*)(ws + off);  off += (size_t)B_ * N_ * 4;
    float* Ek  = (float*)(ws + off);  off += (size_t)B_ * N_ * 4;
    float* eks = (float*)(ws + off);  off += (size_t)B_ * N_ * 4;
    unsigned int* bits = (unsigned int*)(ws + off); off += (size_t)N_ * 64 * 4; // 512 KB

    hipMemsetAsync(denom, 0, (size_t)B_ * N_ * 4, stream);

    k_pack_adj<<<N_ * N_ / 256, 256, 0, stream>>>(adj, bits);
    k_emb<<<dim3(N_ / 64, B_), 256, 0, stream>>>(x, W, be, wq, bq, wk, bk,
                                                 Pb, qa, ka, Eq, eqs, Ek, eks);
    k_denom<<<dim3(8, 16, 8), 256, 0, stream>>>(bits, qa, ka, Eq, eqs, Ek, eks, denom);
    k_attn<<<dim3(N_ / 64, B_), 256, 0, stream>>>(Eq, eqs, Ek, eks, denom, bits, Pb, out);
}

// Round 7
// 187.100 us; speedup vs baseline: 1.1134x; 1.1134x over previous
//
#include <hip/hip_runtime.h>
#include <hip/hip_bf16.h>
#include <stdint.h>

#define B_ 16
#define N_ 2048
#define D_ 128

typedef __bf16 bf16_t;
typedef bf16_t bf16x8 __attribute__((ext_vector_type(8)));
typedef float f32x4 __attribute__((ext_vector_type(4)));

// ---------------- K0: pack adj (fp32 0/1 matrix) into bitmask ----------------
__global__ __launch_bounds__(256) void k_pack_adj(const float* __restrict__ adj,
                                                  unsigned int* __restrict__ bits) {
    int t = blockIdx.x * 256 + threadIdx.x;       // over N*N
    float v = adj[t];
    unsigned long long m = __ballot(v > 0.5f);
    if ((t & 63) == 0) {
        int i = t >> 11;
        int j = t & 2047;
        bits[i * 64 + (j >> 5)]     = (unsigned int)m;
        bits[i * 64 + (j >> 5) + 1] = (unsigned int)(m >> 32);
    }
}

// ---------------- K1: emb GEMM (64n x 128d tile) + fused q/k + exps ----------
// Pb[b][d][n] = bf16( sum_k x[b][n][k]*W[d][k] + be[d] )   (raw seq_fts, bf16)
__global__ __launch_bounds__(256, 2) void k_emb(const float* __restrict__ x,
                                                const float* __restrict__ W,
                                                const float* __restrict__ be,
                                                const float* __restrict__ wq,
                                                const float* __restrict__ bq,
                                                const float* __restrict__ wk,
                                                const float* __restrict__ bk,
                                                bf16_t* __restrict__ Pb,
                                                float* __restrict__ qa, float* __restrict__ ka,
                                                float* __restrict__ Eq, float* __restrict__ eqs,
                                                float* __restrict__ Ek, float* __restrict__ eks) {
    __shared__ float xs[32][68];     // [k][n]  64n + pad
    __shared__ float ws[32][132];    // [k][d]  128d + pad
    __shared__ float qs[64], ks[64];
    int b  = blockIdx.y;
    int n0 = blockIdx.x * 64;
    int tid = threadIdx.x;
    int tx = tid & 15, ty = tid >> 4;   // tx: n-dir (4 n), ty: d-dir (8 d)
    if (tid < 64) { qs[tid] = 0.f; ks[tid] = 0.f; }

    float acc[4][8] = {};               // [n][d]
    f32x4 xr[2], wr[4];

    auto loadregs = [&](int kc) {
#pragma unroll
        for (int s = 0; s < 2; ++s) {
            int p = tid + 256 * s;
            int n = p >> 3, kq = p & 7;
            xr[s] = *(const f32x4*)(x + ((size_t)(b * N_ + n0 + n)) * D_ + kc * 32 + kq * 4);
        }
#pragma unroll
        for (int s = 0; s < 4; ++s) {
            int p = tid + 256 * s;
            int d = p >> 3, kq = p & 7;
            wr[s] = *(const f32x4*)(W + (size_t)d * D_ + kc * 32 + kq * 4);
        }
    };
    auto writelds = [&]() {
#pragma unroll
        for (int s = 0; s < 2; ++s) {
            int p = tid + 256 * s;
            int n = p >> 3, kq = p & 7;
#pragma unroll
            for (int u = 0; u < 4; ++u) xs[kq * 4 + u][n] = xr[s][u];
        }
#pragma unroll
        for (int s = 0; s < 4; ++s) {
            int p = tid + 256 * s;
            int d = p >> 3, kq = p & 7;
#pragma unroll
            for (int u = 0; u < 4; ++u) ws[kq * 4 + u][d] = wr[s][u];
        }
    };

    loadregs(0);
    for (int kc = 0; kc < 4; ++kc) {
        writelds();
        __syncthreads();
        if (kc < 3) loadregs(kc + 1);
#pragma unroll 4
        for (int k = 0; k < 32; ++k) {
            f32x4 xv  = *(const f32x4*)&xs[k][tx * 4];
            f32x4 wv0 = *(const f32x4*)&ws[k][ty * 8];
            f32x4 wv1 = *(const f32x4*)&ws[k][ty * 8 + 4];
#pragma unroll
            for (int i = 0; i < 4; ++i)
#pragma unroll
                for (int j = 0; j < 8; ++j)
                    acc[i][j] += xv[i] * ((j < 4) ? wv0[j] : wv1[j - 4]);
        }
        __syncthreads();
    }

    float qp[4] = {}, kp[4] = {};
#pragma unroll
    for (int j = 0; j < 8; ++j) {
        int d = ty * 8 + j;
        float bj  = be[d];
        float wqj = wq[d];
        float wkj = wk[d];
        f32x4 o;
        bf16_t ob[4];
#pragma unroll
        for (int i = 0; i < 4; ++i) {
            o[i] = acc[i][j] + bj;
            qp[i] += o[i] * wqj;
            kp[i] += o[i] * wkj;
            ob[i] = (bf16_t)o[i];
        }
        *(uint2*)(Pb + ((size_t)b * D_ + d) * N_ + n0 + tx * 4) = *(uint2*)ob;
    }
#pragma unroll
    for (int i = 0; i < 4; ++i) {
        atomicAdd(&qs[tx * 4 + i], qp[i]);
        atomicAdd(&ks[tx * 4 + i], kp[i]);
    }
    __syncthreads();
    if (tid < 64) {
        int idx = b * N_ + n0 + tid;
        float aq = qs[tid] + bq[0];
        float ak = ks[tid] + bk[0];
        qa[idx] = aq;          ka[idx] = ak;
        Eq[idx] = expf(aq);    eqs[idx] = expf(0.01f * aq);
        Ek[idx] = expf(ak);    eks[idx] = expf(0.01f * ak);
    }
}

// ---------------- K2: denom[b][j] = sum_i V(b,i,j) ---------------------------
__global__ __launch_bounds__(256) void k_denom(const unsigned int* __restrict__ bits,
                                               const float* __restrict__ qa,
                                               const float* __restrict__ ka,
                                               const float* __restrict__ Eq,
                                               const float* __restrict__ eqs,
                                               const float* __restrict__ Ek,
                                               const float* __restrict__ eks,
                                               float* __restrict__ denom) {
    int jt  = blockIdx.x;     // 0..7
    int b   = blockIdx.y;     // 0..15
    int seg = blockIdx.z;     // 0..7
    int j = jt * 256 + threadIdx.x;
    float qj  = qa[b * N_ + j];
    float Eqj = Eq[b * N_ + j];
    float eqj = eqs[b * N_ + j];
    int shift = j & 31;
    int wid   = j >> 5;
    float acc = 0.f;
    int i0 = seg * 256;
#pragma unroll 16
    for (int i = i0; i < i0 + 256; ++i) {
        float kk  = ka[b * N_ + i];
        float Ekk = Ek[b * N_ + i];
        float ekk = eks[b * N_ + i];
        unsigned int w = bits[i * 64 + wid];
        float z  = kk + qj;
        float f1 = z > 0.f ? Ekk : ekk;
        float f2 = z > 0.f ? Eqj : eqj;
        float v  = f1 * f2;
        acc += ((w >> shift) & 1u) ? v : 1.0f;
    }
    atomicAdd(&denom[b * N_ + j], acc);
}

// ---------------- K2b: rd = 1/denom; Eqr = Eq*rd; eqr = eqs*rd ---------------
__global__ __launch_bounds__(256) void k_post(const float* __restrict__ denom,
                                              const float* __restrict__ Eq,
                                              const float* __restrict__ eqs,
                                              float* __restrict__ rd,
                                              float* __restrict__ Eqr,
                                              float* __restrict__ eqr) {
    int t = blockIdx.x * 256 + threadIdx.x;   // over B*N
    float r = 1.0f / denom[t];
    rd[t]  = r;
    Eqr[t] = Eq[t] * r;
    eqr[t] = eqs[t] * r;
}

// ---------------- K3: vals = A' @ P ------------------------------------------
// A'[i,j] = edge ? (z>0?Ek_i:ek_i)*(z>0?Eqr_j:eqr_j) : rd_j   (5 VALU/elem)
// Block 64i x 128d, 4 waves (ig,dg) = 32i x 64d, grid 512 (2 blocks/CU).
// A-gen DEDUP: wave generates only j-half hh=dg for its 2 i-chunks (keeps in
// regs, writes to ldsA), reads the other half from ldsA after a raw
// lgkm-only barrier (B prefetch vmcnt stays in flight).
// j-side inputs register-pipelined one step ahead (no intra-step waits).
__global__ __launch_bounds__(256, 2) void k_attn(const float* __restrict__ qa,
                                                 const float* __restrict__ ka,
                                                 const float* __restrict__ Ek,
                                                 const float* __restrict__ eks,
                                                 const float* __restrict__ rd,
                                                 const float* __restrict__ Eqr,
                                                 const float* __restrict__ eqr,
                                                 const unsigned int* __restrict__ bits,
                                                 const bf16_t* __restrict__ Pb,
                                                 float* __restrict__ out) {
    __shared__ __align__(16) bf16_t ldsB[2][128 * 64];    // 32 KB, B dbuf
    __shared__ __align__(16) bf16_t ldsA[4 * 2 * 64 * 8]; // 8 KB, A exchange
    int b     = blockIdx.y;
    int ibase = blockIdx.x * 64;
    int tid   = threadIdx.x;
    int w     = tid >> 6;          // 0..3
    int lane  = tid & 63;
    int m16   = lane & 15;
    int quad  = lane >> 4;
    int ig    = w & 1;             // i-group (32 i)
    int dg    = w >> 1;            // d-group (64 d); also my j-half hh

    int iA = ibase + (2 * ig) * 16 + m16;
    int iB = iA + 16;
    float mkR0 = -ka[b * N_ + iA], mkR1 = -ka[b * N_ + iB];   // z>0 <=> q_j > -k_i
    float EkR0 = Ek[b * N_ + iA],  EkR1 = Ek[b * N_ + iB];
    float ekR0 = eks[b * N_ + iA], ekR1 = eks[b * N_ + iB];
    const unsigned int* brA = bits + (size_t)iA * 64;
    const unsigned int* brB = bits + (size_t)iB * 64;
    const float* qp  = qa  + b * N_;
    const float* Erp = Eqr + b * N_;
    const float* erp = eqr + b * N_;
    const float* rdp = rd  + b * N_;
    const bf16_t* PtB = Pb + (size_t)b * D_ * N_;

    f32x4 acc[2][4];   // [i-chunk][d-tile]
#pragma unroll
    for (int c = 0; c < 2; ++c)
#pragma unroll
        for (int nt = 0; nt < 4; ++nt) acc[c][nt] = (f32x4){0.f, 0.f, 0.f, 0.f};

    // ---- pipeline registers (parity-indexed; compile-time after unroll) ----
    f32x4 qv4[2][2], Er4[2][2], er4[2][2], rd4[2][2];  // [par][half4] (own hh only)
    unsigned int mA[2], mB[2];

    auto ldj = [&](int par, int jb) {
        int j0 = jb + dg * 32 + quad * 8;
        qv4[par][0] = *(const f32x4*)(qp  + j0);
        qv4[par][1] = *(const f32x4*)(qp  + j0 + 4);
        Er4[par][0] = *(const f32x4*)(Erp + j0);
        Er4[par][1] = *(const f32x4*)(Erp + j0 + 4);
        er4[par][0] = *(const f32x4*)(erp + j0);
        er4[par][1] = *(const f32x4*)(erp + j0 + 4);
        rd4[par][0] = *(const f32x4*)(rdp + j0);
        rd4[par][1] = *(const f32x4*)(rdp + j0 + 4);
        mA[par] = brA[(jb >> 5) + dg];
        mB[par] = brB[(jb >> 5) + dg];
    };

    // Stage 128d x 64j bf16 tile (16 KB), XOR swizzle on the GLOBAL address.
    auto stage = [&](int bufi, int jb) {
#pragma unroll
        for (int t = 0; t < 4; ++t) {
            int off = t * 4096 + tid * 16;               // byte offset in tile
            int d   = off >> 7;                          // row (128 B = 64 j)
            int g   = ((off & 127) >> 4) ^ (d & 7);      // swizzled j-chunk
            const bf16_t* gp = PtB + (size_t)d * N_ + jb + g * 8;
            __builtin_amdgcn_global_load_lds(
                (const __attribute__((address_space(1))) void*)gp,
                (__attribute__((address_space(3))) void*)((char*)(&ldsB[bufi][0]) + off),
                16, 0, 0);
        }
    };

    stage(0, 0);
    ldj(0, 0);
    __syncthreads();                 // drain initial stage + step-0 regs
    int buf = 0;
#pragma unroll 1
    for (int s2 = 0; s2 < N_ / 128; ++s2) {
#pragma unroll
        for (int par = 0; par < 2; ++par) {
            int step = s2 * 2 + par;
            int jb = step * 64;
            if (step + 1 < N_ / 64) {
                ldj(par ^ 1, jb + 64);       // j-side regs for next step
                stage(buf ^ 1, jb + 64);     // B prefetch for next step
            }

            // ---- A-gen: own hh only, both i-chunks, from registers ----
            bf16x8 afA, afB;
#pragma unroll
            for (int t = 0; t < 8; ++t) {
                float qv = (t < 4) ? qv4[par][0][t] : qv4[par][1][t - 4];
                float Er = (t < 4) ? Er4[par][0][t] : Er4[par][1][t - 4];
                float er = (t < 4) ? er4[par][0][t] : er4[par][1][t - 4];
                float rj = (t < 4) ? rd4[par][0][t] : rd4[par][1][t - 4];
                int bit = quad * 8 + t;
                {
                    bool c = qv > mkR0;
                    float v = (c ? EkR0 : ekR0) * (c ? Er : er);
                    afA[t] = (bf16_t)(((mA[par] >> bit) & 1u) ? v : rj);
                }
                {
                    bool c = qv > mkR1;
                    float v = (c ? EkR1 : ekR1) * (c ? Er : er);
                    afB[t] = (bf16_t)(((mB[par] >> bit) & 1u) ? v : rj);
                }
            }
            // publish own frags: ldsA[chunk][hh][lane]
            *(bf16x8*)((char*)ldsA + ((((2 * ig + 0) * 2 + dg) * 64 + lane) * 16)) = afA;
            *(bf16x8*)((char*)ldsA + ((((2 * ig + 1) * 2 + dg) * 64 + lane) * 16)) = afB;

            // raw barrier: drain LDS only — B prefetch (vmcnt) stays in flight
            asm volatile("s_waitcnt lgkmcnt(0)\n\ts_barrier" ::: "memory");

            // ---- MFMA: own hh from regs, other hh from ldsA ----
            {
                int cph = ((dg * 4 + quad) ^ (m16 & 7)) * 8;
#pragma unroll
                for (int nt = 0; nt < 4; ++nt) {
                    int d = dg * 64 + nt * 16 + m16;
                    bf16x8 bf = *(const bf16x8*)&ldsB[buf][d * 64 + cph];
                    acc[0][nt] = __builtin_amdgcn_mfma_f32_16x16x32_bf16(afA, bf, acc[0][nt], 0, 0, 0);
                    acc[1][nt] = __builtin_amdgcn_mfma_f32_16x16x32_bf16(afB, bf, acc[1][nt], 0, 0, 0);
                }
            }
            {
                int oh = 1 - dg;
                bf16x8 a0 = *(const bf16x8*)((char*)ldsA + ((((2 * ig + 0) * 2 + oh) * 64 + lane) * 16));
                bf16x8 a1 = *(const bf16x8*)((char*)ldsA + ((((2 * ig + 1) * 2 + oh) * 64 + lane) * 16));
                int cph = ((oh * 4 + quad) ^ (m16 & 7)) * 8;
#pragma unroll
                for (int nt = 0; nt < 4; ++nt) {
                    int d = dg * 64 + nt * 16 + m16;
                    bf16x8 bf = *(const bf16x8*)&ldsB[buf][d * 64 + cph];
                    acc[0][nt] = __builtin_amdgcn_mfma_f32_16x16x32_bf16(a0, bf, acc[0][nt], 0, 0, 0);
                    acc[1][nt] = __builtin_amdgcn_mfma_f32_16x16x32_bf16(a1, bf, acc[1][nt], 0, 0, 0);
                }
            }
            __syncthreads();   // drains next-step prefetch + guards lds reuse
            buf ^= 1;
        }
    }

    // ---- epilogue: C layout col=lane&15 (d), row=quad*4+r (i) ----
#pragma unroll
    for (int c = 0; c < 2; ++c) {
        int irow = ibase + (2 * ig + c) * 16 + quad * 4;
#pragma unroll
        for (int nt = 0; nt < 4; ++nt) {
            int d = dg * 64 + nt * 16 + m16;
#pragma unroll
            for (int r = 0; r < 4; ++r)
                out[((size_t)b * N_ + irow + r) * D_ + d] = acc[c][nt][r];
        }
    }
}

extern "C" void kernel_launch(void* const* d_in, const int* in_sizes, int n_in,
                              void* d_out, int out_size, void* d_ws, size_t ws_size,
                              hipStream_t stream) {
    const float* x   = (const float*)d_in[0];
    const float* adj = (const float*)d_in[1];
    const float* W   = (const float*)d_in[2];
    const float* be  = (const float*)d_in[3];
    const float* wq  = (const float*)d_in[4];
    const float* bq  = (const float*)d_in[5];
    const float* wk  = (const float*)d_in[6];
    const float* bk  = (const float*)d_in[7];
    float* out = (float*)d_out;

    char* ws = (char*)d_ws;
    size_t off = 0;
    bf16_t* Pb = (bf16_t*)(ws + off); off += (size_t)B_ * D_ * N_ * 2;   // 8 MB
    float* qa  = (float*)(ws + off);  off += (size_t)B_ * N_ * 4;
    float* ka  = (float*)(ws + off);  off += (size_t)B_ * N_ * 4;
    float* denom = (float*)(ws + off); off += (size_t)B_ * N_ * 4;
    float* Eq  = (float*)(ws + off);  off += (size_t)B_ * N_ * 4;
    float* eqs = (float*)(ws + off);  off += (size_t)B_ * N_ * 4;
    float* Ek  = (float*)(ws + off);  off += (size_t)B_ * N_ * 4;
    float* eks = (float*)(ws + off);  off += (size_t)B_ * N_ * 4;
    float* rd  = (float*)(ws + off);  off += (size_t)B_ * N_ * 4;
    float* Eqr = (float*)(ws + off);  off += (size_t)B_ * N_ * 4;
    float* eqr = (float*)(ws + off);  off += (size_t)B_ * N_ * 4;
    unsigned int* bits = (unsigned int*)(ws + off); off += (size_t)N_ * 64 * 4; // 512 KB

    hipMemsetAsync(denom, 0, (size_t)B_ * N_ * 4, stream);

    k_pack_adj<<<N_ * N_ / 256, 256, 0, stream>>>(adj, bits);
    k_emb<<<dim3(N_ / 64, B_), 256, 0, stream>>>(x, W, be, wq, bq, wk, bk,
                                                 Pb, qa, ka, Eq, eqs, Ek, eks);
    k_denom<<<dim3(8, 16, 8), 256, 0, stream>>>(bits, qa, ka, Eq, eqs, Ek, eks, denom);
    k_post<<<B_ * N_ / 256, 256, 0, stream>>>(denom, Eq, eqs, rd, Eqr, eqr);
    k_attn<<<dim3(N_ / 64, B_), 256, 0, stream>>>(qa, ka, Ek, eks, rd, Eqr, eqr,
                                                  bits, Pb, out);
}